// Round 7
// baseline (4165.701 us; speedup 1.0000x reference)
//
#include <hip/hip_runtime.h>
#include <stdint.h>

typedef unsigned short u16;
typedef unsigned int u32;
typedef __attribute__((ext_vector_type(8))) short short8;
typedef __attribute__((ext_vector_type(4))) float f32x4;

#define T_SEQ 1024
#define HDIM  1024
#define NG    3072
#define SLOT  16384          // u16 elements per time-slot: 64 strips * 16 batch * 16 cols
#define FSTRIDE 32           // u32 stride between flags (128 B, own line)

__device__ __forceinline__ u16 f2bf(float f) {
  unsigned u = __float_as_uint(f);
  u += 0x7FFF + ((u >> 16) & 1);
  return (u16)(u >> 16);
}
__device__ __forceinline__ float bf2f(u16 h) {
  return __uint_as_float(((unsigned)h) << 16);
}

// bank-conflict-free part[] row permutation (proven: conflicts 1.9e7 -> 0 in R6)
__device__ __forceinline__ int prow(int b) { return b ^ ((b >> 2) & 1); }

// async global->LDS, 16B per lane (GEMM staging only).
__device__ __forceinline__ void gld16(void* lds, const void* g) {
  __builtin_amdgcn_global_load_lds(
      (const __attribute__((address_space(1))) unsigned*)g,
      (__attribute__((address_space(3))) unsigned*)lds, 16, 0, 0);
}

__device__ __forceinline__ void st_agent_u32(unsigned* p, unsigned v) {
  __hip_atomic_store(p, v, __ATOMIC_RELAXED, __HIP_MEMORY_SCOPE_AGENT);
}
__device__ __forceinline__ unsigned ld_agent_u32(const unsigned* p) {
  return __hip_atomic_load(p, __ATOMIC_RELAXED, __HIP_MEMORY_SCOPE_AGENT);
}

// all 64 lanes poll one wave-flag each: wave w's K-slice = producer WGs 16w..16w+15,
// x4 waves each = 64 wave-flags = 1 per lane. Divergent spin.
__device__ __forceinline__ void poll64(const unsigned* flags, int wave, int lane, unsigned need) {
  const unsigned* f = flags + (size_t)(64 * wave + lane) * FSTRIDE;
  while (ld_agent_u32(f) < need) {}
  asm volatile("" ::: "memory");
}

// ---------------- prep: cast 5 weight tensors fp32->bf16, zero flags ------------
__global__ void cast5_kernel(const float* __restrict__ s0, const float* __restrict__ s1,
                             const float* __restrict__ s2, const float* __restrict__ s3,
                             const float* __restrict__ s4,
                             u16* __restrict__ d0, u16* __restrict__ d1,
                             u16* __restrict__ d2, u16* __restrict__ d3,
                             u16* __restrict__ d4, unsigned* __restrict__ flags) {
  if (blockIdx.x == 0) {
#pragma unroll
    for (int k = 0; k < 64; ++k) flags[threadIdx.x * 64 + k] = 0;  // 64 KB of flags
  }
  int bid = blockIdx.x;
  const float* s; u16* d; size_t base;
  if (bid < 3072)       { s = s0; d = d0; base = (size_t)bid * 1024; }
  else if (bid < 6144)  { s = s1; d = d1; base = (size_t)(bid - 3072) * 1024; }
  else if (bid < 9216)  { s = s2; d = d2; base = (size_t)(bid - 6144) * 1024; }
  else if (bid < 12288) { s = s3; d = d3; base = (size_t)(bid - 9216) * 1024; }
  else                  { s = s4; d = d4; base = (size_t)(bid - 12288) * 1024; }
  size_t i = base + (size_t)threadIdx.x * 4;
  float4 v = *(const float4*)(s + i);
  unsigned lo = (unsigned)f2bf(v.x) | ((unsigned)f2bf(v.y) << 16);
  unsigned hi = (unsigned)f2bf(v.z) | ((unsigned)f2bf(v.w) << 16);
  uint2 o; o.x = lo; o.y = hi;
  *(uint2*)(d + i) = o;
}

// ---------------- embedding gather + cast to bf16 ------------------------------
__global__ void gather_cast_kernel(const int* __restrict__ tokens,
                                   const float* __restrict__ emb,
                                   u16* __restrict__ xbf) {
  int row = blockIdx.x;                 // 0..16383  (= b*T + t)
  int tok = tokens[row];
  const float4* src = (const float4*)(emb + (size_t)tok * HDIM);
  float4 v = src[threadIdx.x];
  unsigned lo = (unsigned)f2bf(v.x) | ((unsigned)f2bf(v.y) << 16);
  unsigned hi = (unsigned)f2bf(v.z) | ((unsigned)f2bf(v.w) << 16);
  uint2 o; o.x = lo; o.y = hi;
  *(uint2*)(xbf + (size_t)row * HDIM + (size_t)threadIdx.x * 4) = o;
}

// ---------------- bf16 MFMA GEMM, C[m,n] = sum_k A[m,k]*Bt[n,k] -----------------
// A_PACKED: A is the packed scan layout h[t][prod][b][16]; logical row r = b*T+t
// maps to slot t+1 (h2_out[t] = h2seq[t+1]).
// OUT_MODE 0: fp32 plain [m*N+n].  OUT_MODE 2: bf16 gx-packed gx[t][wg][gate][b][ej].
template <int OUT_MODE, bool A_PACKED, bool ADD_BIAS>
__global__ __launch_bounds__(256)
void gemm_bt(const u16* __restrict__ A, const u16* __restrict__ Bt,
             void* __restrict__ Cout, const float* __restrict__ bias,
             int M, int N) {
  const int K = 1024;
  __shared__ u16 As[128 * 32];
  __shared__ u16 Bs[128 * 32];
  const int tid = threadIdx.x;
  const int wave = tid >> 6, lane = tid & 63;
  const int quad = lane >> 4, l16 = lane & 15;
  const int wm = (wave & 1) * 64, wn = (wave >> 1) * 64;
  const int m0 = blockIdx.x * 128, n0 = blockIdx.y * 128;
  const int srow = tid >> 2, scol = (tid & 3) * 8;

  size_t abase0, abase1;
  {
    int r0 = m0 + srow, r1 = m0 + 64 + srow;
    if (A_PACKED) {
      abase0 = (size_t)((r0 & 1023) + 1) * SLOT + (size_t)(r0 >> 10) * 16 +
               (size_t)(scol & 8) + (size_t)(scol >> 4) * 256;
      abase1 = (size_t)((r1 & 1023) + 1) * SLOT + (size_t)(r1 >> 10) * 16 +
               (size_t)(scol & 8) + (size_t)(scol >> 4) * 256;
    } else {
      abase0 = (size_t)r0 * K + scol;
      abase1 = (size_t)r1 * K + scol;
    }
  }
  const size_t bbase0 = (size_t)(n0 + srow) * K + scol;
  const size_t bbase1 = (size_t)(n0 + 64 + srow) * K + scol;

  f32x4 acc[4][4] = {};

  for (int kk = 0; kk < K; kk += 32) {
    __syncthreads();
    size_t ka = A_PACKED ? (size_t)kk * 16 : (size_t)kk;   // 32 cols = 2 strips = 512 elems
    gld16(&As[srow * 32 + scol],        A + abase0 + ka);
    gld16(&As[(64 + srow) * 32 + scol], A + abase1 + ka);
    gld16(&Bs[srow * 32 + scol],        Bt + bbase0 + kk);
    gld16(&Bs[(64 + srow) * 32 + scol], Bt + bbase1 + kk);
    __syncthreads();
    short8 af[4], bfr[4];
#pragma unroll
    for (int mt = 0; mt < 4; ++mt)
      af[mt] = *(const short8*)&As[(wm + mt * 16 + l16) * 32 + quad * 8];
#pragma unroll
    for (int nt = 0; nt < 4; ++nt)
      bfr[nt] = *(const short8*)&Bs[(wn + nt * 16 + l16) * 32 + quad * 8];
#pragma unroll
    for (int mt = 0; mt < 4; ++mt)
#pragma unroll
      for (int nt = 0; nt < 4; ++nt)
        acc[mt][nt] = __builtin_amdgcn_mfma_f32_16x16x32_bf16(af[mt], bfr[nt], acc[mt][nt], 0, 0, 0);
  }
#pragma unroll
  for (int mt = 0; mt < 4; ++mt) {
#pragma unroll
    for (int nt = 0; nt < 4; ++nt) {
#pragma unroll
      for (int r = 0; r < 4; ++r) {
        int m = m0 + wm + mt * 16 + quad * 4 + r;
        int n = n0 + wn + nt * 16 + l16;
        float v = acc[mt][nt][r];
        if (ADD_BIAS) v += bias[n];
        if (OUT_MODE == 2) {
          int t = m & 1023, b = m >> 10, g = n >> 10, c = n & 1023;
          size_t idx = ((((size_t)t * 64 + (c >> 4)) * 3 + g) * 16 + b) * 16 + (c & 15);
          ((u16*)Cout)[idx] = f2bf(v);
        } else {
          ((float*)Cout)[(size_t)m * N + n] = v;
        }
      }
    }
  }
}

// ---------------- fused MERGED 2-layer persistent GRU scan, 64 WGs --------------
// Combined step t: L0 step t (t<1024) + L1 step t-1 (t>0). ONE flag system:
// wave-flag v certifies {h1seq[v-1], h2seq[v-2]} published by that wave's batches.
// af1 = h1seq[t] fragments feed BOTH L0-h matvec and L1-x matvec (one load, two
// uses); af2 = h2seq[t-1]. 9-way part reduce, single-buffered, two barriers:
// barrier A = __syncthreads (implicit vmcnt free: af/gx long consumed);
// barrier B = raw s_barrier (NO vmcnt drain -> flag store + gx prefetch stay in
// flight). Weights: Whh0+Whh1 slices in VGPRs, Wih1 slice in LDS (96 KB).
__global__ __launch_bounds__(256, 1)
void fused_scan_kernel(const u16* __restrict__ gx0,
                       u16* __restrict__ h1seq, u16* __restrict__ h2seq,
                       const u16* __restrict__ Whh0, const u16* __restrict__ Wih1,
                       const u16* __restrict__ Whh1,
                       const float* __restrict__ bih0, const float* __restrict__ bhh0,
                       const float* __restrict__ bih1, const float* __restrict__ bhh1,
                       unsigned* __restrict__ flags) {
  const int tid = threadIdx.x;
  const int wave = tid >> 6, lane = tid & 63;
  const int quad = lane >> 4, l16 = lane & 15;
  const int eb = tid >> 4, ej = tid & 15;

  __shared__ float part[4][9][256];            // 36 KB, single-buffered
  __shared__ float biasS[4][3][16];            // [bih0, bhh0, bih1, bhh1]
  __shared__ u16 wx[4 * 3 * 8 * 4 * 16 * 8];   // 96 KB, Wih1 slice

  // fragment source offset within a slot: prod = 16w + 2s + (quad>>1),
  // elem = prod*256 + batch(l16)*16 + (quad&1)*8 ; + s*512 per k-subtile
  const int fragoff = (16 * wave + (quad >> 1)) * 256 + l16 * 16 + (quad & 1) * 8;
  const int rdo = prow(eb) * 16 + ej;          // swizzled part[] read offset

  const int wg = blockIdx.x, j0 = wg * 16;
  short8 wf0[3][8], wfH[3][8];
#pragma unroll
  for (int g = 0; g < 3; ++g)
#pragma unroll
    for (int s = 0; s < 8; ++s) {
      size_t row = (size_t)(g * 1024 + j0 + l16) * 1024 + wave * 256 + s * 32 + quad * 8;
      wf0[g][s] = *(const short8*)&Whh0[row];
      wfH[g][s] = *(const short8*)&Whh1[row];
      short8 wv = *(const short8*)&Wih1[row];   // stage to LDS (own slot, no barrier)
      *(short8*)&wx[((((wave * 3 + g) * 8 + s) * 4 + quad) * 16 + l16) * 8] = wv;
    }
  if (tid < 192) {
    int a = tid / 48, rem = tid % 48, g = rem >> 4, jl = rem & 15;
    const float* src = (a == 0) ? bih0 : (a == 1) ? bhh0 : (a == 2) ? bih1 : bhh1;
    biasS[a][g][jl] = src[g * 1024 + j0 + jl];
  }
  // zero own 128B chunks of h1seq[0] and h2seq[0]; drain; wave-flag = 1
  if (lane < 32) {
    st_agent_u32((unsigned*)h1seq + wg * 128 + wave * 32 + lane, 0u);
    st_agent_u32((unsigned*)h2seq + wg * 128 + wave * 32 + lane, 0u);
  }
  asm volatile("s_waitcnt vmcnt(0)" ::: "memory");
  if (lane == 0) st_agent_u32(flags + (size_t)(wg * 4 + wave) * FSTRIDE, 1u);

  const u16* gxp = gx0 + (size_t)(wg * 3) * 256 + eb * 16 + ej;   // t = 0
  u16 gxu0 = gxp[0], gxu1 = gxp[256], gxu2 = gxp[512];
  float hp1 = 0.f, hp2 = 0.f;

  for (int t = 0; t <= T_SEQ; ++t) {
    poll64(flags, wave, lane, (unsigned)(t + 1));
    short8 af1[8], af2[8];
    {
      const u16* s1 = h1seq + (size_t)t * SLOT + fragoff;
#pragma unroll
      for (int s = 0; s < 8; ++s) af1[s] = *(const short8*)(s1 + s * 512);
    }
    if (t > 0) {
      const u16* s2 = h2seq + (size_t)(t - 1) * SLOT + fragoff;
#pragma unroll
      for (int s = 0; s < 8; ++s) af2[s] = *(const short8*)(s2 + s * 512);
    }
    f32x4 a0 = {0.f,0.f,0.f,0.f}, a1 = {0.f,0.f,0.f,0.f}, a2 = {0.f,0.f,0.f,0.f};
    f32x4 x0 = {0.f,0.f,0.f,0.f}, x1 = {0.f,0.f,0.f,0.f}, x2 = {0.f,0.f,0.f,0.f};
    f32x4 h0 = {0.f,0.f,0.f,0.f}, h1a = {0.f,0.f,0.f,0.f}, h2a = {0.f,0.f,0.f,0.f};
    if (t < T_SEQ) {
#pragma unroll
      for (int s = 0; s < 8; ++s) {
        a0 = __builtin_amdgcn_mfma_f32_16x16x32_bf16(af1[s], wf0[0][s], a0, 0, 0, 0);
        a1 = __builtin_amdgcn_mfma_f32_16x16x32_bf16(af1[s], wf0[1][s], a1, 0, 0, 0);
        a2 = __builtin_amdgcn_mfma_f32_16x16x32_bf16(af1[s], wf0[2][s], a2, 0, 0, 0);
      }
    }
    if (t > 0) {
#pragma unroll
      for (int s = 0; s < 8; ++s) {
        short8 w0 = *(const short8*)&wx[((((wave * 3 + 0) * 8 + s) * 4 + quad) * 16 + l16) * 8];
        short8 w1 = *(const short8*)&wx[((((wave * 3 + 1) * 8 + s) * 4 + quad) * 16 + l16) * 8];
        short8 w2 = *(const short8*)&wx[((((wave * 3 + 2) * 8 + s) * 4 + quad) * 16 + l16) * 8];
        x0 = __builtin_amdgcn_mfma_f32_16x16x32_bf16(af1[s], w0, x0, 0, 0, 0);
        x1 = __builtin_amdgcn_mfma_f32_16x16x32_bf16(af1[s], w1, x1, 0, 0, 0);
        x2 = __builtin_amdgcn_mfma_f32_16x16x32_bf16(af1[s], w2, x2, 0, 0, 0);
        h0  = __builtin_amdgcn_mfma_f32_16x16x32_bf16(af2[s], wfH[0][s], h0, 0, 0, 0);
        h1a = __builtin_amdgcn_mfma_f32_16x16x32_bf16(af2[s], wfH[1][s], h1a, 0, 0, 0);
        h2a = __builtin_amdgcn_mfma_f32_16x16x32_bf16(af2[s], wfH[2][s], h2a, 0, 0, 0);
      }
    }
#pragma unroll
    for (int r = 0; r < 4; ++r) {
      int o = prow(quad * 4 + r) * 16 + l16;
      if (t < T_SEQ) {
        part[wave][0][o] = a0[r]; part[wave][1][o] = a1[r]; part[wave][2][o] = a2[r];
      }
      if (t > 0) {
        part[wave][3][o] = x0[r]; part[wave][4][o] = x1[r]; part[wave][5][o] = x2[r];
        part[wave][6][o] = h0[r]; part[wave][7][o] = h1a[r]; part[wave][8][o] = h2a[r];
      }
    }
    __syncthreads();   // barrier A (implicit vmcnt free: af consumed, gx/flag old)

    unsigned m1 = 0, m2 = 0;
    if (t < T_SEQ) {   // L0 gates -> h1_out[t]
      float ghr = part[0][0][rdo] + part[1][0][rdo] + part[2][0][rdo] + part[3][0][rdo] + biasS[1][0][ej];
      float ghz = part[0][1][rdo] + part[1][1][rdo] + part[2][1][rdo] + part[3][1][rdo] + biasS[1][1][ej];
      float ghn = part[0][2][rdo] + part[1][2][rdo] + part[2][2][rdo] + part[3][2][rdo] + biasS[1][2][ej];
      float xr = bf2f(gxu0) + biasS[0][0][ej] + ghr;
      float xz = bf2f(gxu1) + biasS[0][1][ej] + ghz;
      float xn = bf2f(gxu2) + biasS[0][2][ej];
      float r_ = 1.f / (1.f + __expf(-xr));
      float z_ = 1.f / (1.f + __expf(-xz));
      float pre = fminf(fmaxf(xn + r_ * ghn, -15.f), 15.f);
      float e2 = __expf(2.f * pre);
      float n_ = (e2 - 1.f) / (e2 + 1.f);
      float hn = (1.f - z_) * n_ + z_ * hp1;
      hp1 = hn; m1 = (unsigned)f2bf(hn);
    }
    if (t > 0) {       // L1 gates -> h2_out[t-1]
      float sxr = part[0][3][rdo] + part[1][3][rdo] + part[2][3][rdo] + part[3][3][rdo] + biasS[2][0][ej];
      float sxz = part[0][4][rdo] + part[1][4][rdo] + part[2][4][rdo] + part[3][4][rdo] + biasS[2][1][ej];
      float sxn = part[0][5][rdo] + part[1][5][rdo] + part[2][5][rdo] + part[3][5][rdo] + biasS[2][2][ej];
      float shr = part[0][6][rdo] + part[1][6][rdo] + part[2][6][rdo] + part[3][6][rdo] + biasS[3][0][ej];
      float shz = part[0][7][rdo] + part[1][7][rdo] + part[2][7][rdo] + part[3][7][rdo] + biasS[3][1][ej];
      float shn = part[0][8][rdo] + part[1][8][rdo] + part[2][8][rdo] + part[3][8][rdo] + biasS[3][2][ej];
      float r_ = 1.f / (1.f + __expf(-(sxr + shr)));
      float z_ = 1.f / (1.f + __expf(-(sxz + shz)));
      float pre = fminf(fmaxf(sxn + r_ * shn, -15.f), 15.f);
      float e2 = __expf(2.f * pre);
      float n_ = (e2 - 1.f) / (e2 + 1.f);
      float hn = (1.f - z_) * n_ + z_ * hp2;
      hp2 = hn; m2 = (unsigned)f2bf(hn);
    }
    unsigned o1 = __shfl_xor(m1, 1), o2 = __shfl_xor(m2, 1);
    if (!(tid & 1)) {
      if (t < T_SEQ)
        st_agent_u32((unsigned*)h1seq + (size_t)(t + 1) * (SLOT / 2) + wg * 128 + (tid >> 1),
                     m1 | (o1 << 16));
      if (t > 0)
        st_agent_u32((unsigned*)h2seq + (size_t)t * (SLOT / 2) + wg * 128 + (tid >> 1),
                     m2 | (o2 << 16));
    }
    asm volatile("s_waitcnt vmcnt(0)" ::: "memory");   // per-wave drain of h stores
    if (lane == 0)
      st_agent_u32(flags + (size_t)(wg * 4 + wave) * FSTRIDE, (unsigned)(t + 2));
    // gx prefetch for step t+1 (after flag: never delays it; in flight across B)
    if (t + 1 < T_SEQ) {
      const u16* gpn = gx0 + (size_t)((t + 1) * 64 + wg) * 3 * 256 + eb * 16 + ej;
      gxu0 = gpn[0]; gxu1 = gpn[256]; gxu2 = gpn[512];
    }
    __builtin_amdgcn_s_barrier();          // barrier B: raw, no vmcnt drain
    __builtin_amdgcn_sched_barrier(0);
  }
}

// ---------------- log_softmax over axis=1 (T): grid (16 b, 8 cgroups) ----------
__global__ void logsoftmax_kernel(float* __restrict__ out) {
  int b = blockIdx.x, cg = blockIdx.y;
  int ci = threadIdx.x & 15, ts = threadIdx.x >> 4;   // 16 cols x 16 t-strips
  int c = cg * 16 + ci;
  float m = -1e30f, s = 0.f;
  for (int t = ts; t < T_SEQ; t += 16) {
    float v = out[((size_t)b * T_SEQ + t) * 128 + c];
    if (v > m) { s = s * __expf(m - v) + 1.f; m = v; }
    else s += __expf(v - m);
  }
  __shared__ float mS[16][16], sS[16][16];
  mS[ts][ci] = m; sS[ts][ci] = s;
  __syncthreads();
  if (ts == 0) {
    float M = mS[0][ci], S = sS[0][ci];
#pragma unroll
    for (int k = 1; k < 16; ++k) {
      float m2 = mS[k][ci], s2 = sS[k][ci];
      float nm = fmaxf(M, m2);
      S = S * __expf(M - nm) + s2 * __expf(m2 - nm);
      M = nm;
    }
    sS[0][ci] = M + logf(S);
  }
  __syncthreads();
  float lsd = sS[0][ci];
  for (int t = ts; t < T_SEQ; t += 16) {
    size_t i = ((size_t)b * T_SEQ + t) * 128 + c;
    out[i] -= lsd;
  }
}

// --------------------------------------------------------------------------------
extern "C" void kernel_launch(void* const* d_in, const int* in_sizes, int n_in,
                              void* d_out, int out_size, void* d_ws, size_t ws_size,
                              hipStream_t stream) {
  const int*   tokens = (const int*)d_in[0];
  const float* emb  = (const float*)d_in[1];
  const float* Wih0 = (const float*)d_in[2];
  const float* Whh0 = (const float*)d_in[3];
  const float* bih0 = (const float*)d_in[4];
  const float* bhh0 = (const float*)d_in[5];
  const float* Wih1 = (const float*)d_in[6];
  const float* Whh1 = (const float*)d_in[7];
  const float* bih1 = (const float*)d_in[8];
  const float* bhh1 = (const float*)d_in[9];
  const float* Wlin = (const float*)d_in[10];
  const float* blin = (const float*)d_in[11];
  float* out = (float*)d_out;

  uint8_t* ws = (uint8_t*)d_ws;
  size_t off = 0;
  auto alloc = [&](size_t bytes) -> void* {
    void* p = ws + off;
    off += (bytes + 255) & ~(size_t)255;
    return p;
  };
  u16* h1seq = (u16*)alloc((size_t)(T_SEQ + 1) * SLOT * 2);  // also holds x_bf pre-scan
  u16* h2seq = (u16*)alloc((size_t)(T_SEQ + 1) * SLOT * 2);
  u16* gxbuf = (u16*)alloc((size_t)16384 * NG * 2);          // packed gx[t][wg][g][b][ej]
  u16* wih0b = (u16*)alloc((size_t)NG * HDIM * 2);
  u16* whh0b = (u16*)alloc((size_t)NG * HDIM * 2);
  u16* wih1b = (u16*)alloc((size_t)NG * HDIM * 2);
  u16* whh1b = (u16*)alloc((size_t)NG * HDIM * 2);
  u16* wlinb = (u16*)alloc((size_t)128 * HDIM * 2);
  unsigned* flags = (unsigned*)alloc(65536);   // 256 wave-flags (one merged set)

  cast5_kernel<<<dim3(12416), dim3(256), 0, stream>>>(
      Wih0, Whh0, Wih1, Whh1, Wlin, wih0b, whh0b, wih1b, whh1b, wlinb, flags);
  gather_cast_kernel<<<dim3(16384), dim3(256), 0, stream>>>(tokens, emb, h1seq);
  // gx0 = x @ W_ih0^T, written consumer-packed
  gemm_bt<2, false, false><<<dim3(128, 24), dim3(256), 0, stream>>>(
      h1seq, wih0b, gxbuf, nullptr, 16384, NG);
  // merged 2-layer scan: 64 WGs, one flag system, one h1 load serves both layers
  fused_scan_kernel<<<dim3(64), dim3(256), 0, stream>>>(
      gxbuf, h1seq, h2seq, whh0b, wih1b, whh1b, bih0, bhh0, bih1, bhh1, flags);
  // logits = h2 @ W_lin^T + b_lin -> d_out (fp32); A read from packed h2 slots
  gemm_bt<0, true, true><<<dim3(128, 1), dim3(256), 0, stream>>>(
      h2seq, wlinb, out, blin, 16384, 128);
  // log_softmax over T, in place
  logsoftmax_kernel<<<dim3(16, 8), dim3(256), 0, stream>>>(out);
}

// Round 8
// 3287.831 us; speedup vs baseline: 1.2670x; 1.2670x over previous
//
#include <hip/hip_runtime.h>
#include <stdint.h>

typedef unsigned short u16;
typedef unsigned int u32;
typedef __attribute__((ext_vector_type(8))) short short8;
typedef __attribute__((ext_vector_type(4))) float f32x4;

#define T_SEQ 1024
#define HDIM  1024
#define NG    3072
#define SLOT  16384          // u16 elements per time-slot: 64 strips * 16 batch * 16 cols
#define FSTRIDE 32           // u32 stride between flags (128 B, own line)

__device__ __forceinline__ u16 f2bf(float f) {
  unsigned u = __float_as_uint(f);
  u += 0x7FFF + ((u >> 16) & 1);
  return (u16)(u >> 16);
}
__device__ __forceinline__ float bf2f(u16 h) {
  return __uint_as_float(((unsigned)h) << 16);
}

// bank-conflict-free part[] row permutation (proven in R6: conflicts 1.9e7 -> 0)
__device__ __forceinline__ int prow(int b) { return b ^ ((b >> 2) & 1); }

// async global->LDS, 16B per lane (GEMM staging only). LDS dest = uniform base + lane*16.
__device__ __forceinline__ void gld16(void* lds, const void* g) {
  __builtin_amdgcn_global_load_lds(
      (const __attribute__((address_space(1))) unsigned*)g,
      (__attribute__((address_space(3))) unsigned*)lds, 16, 0, 0);
}

__device__ __forceinline__ void st_agent_u32(unsigned* p, unsigned v) {
  __hip_atomic_store(p, v, __ATOMIC_RELAXED, __HIP_MEMORY_SCOPE_AGENT);
}
__device__ __forceinline__ unsigned ld_agent_u32(const unsigned* p) {
  return __hip_atomic_load(p, __ATOMIC_RELAXED, __HIP_MEMORY_SCOPE_AGENT);
}

// all 64 lanes poll one wave-flag each (wave's 16 producers x 4 wave-flags = 64):
// flag index (wg*4+wv) = 64*wave + lane. Divergent spin; reconvergence = all done.
__device__ __forceinline__ void poll64(const unsigned* flags, int wave, int lane, unsigned need) {
  const unsigned* f = flags + (size_t)(64 * wave + lane) * FSTRIDE;
  while (ld_agent_u32(f) < need) {}
  asm volatile("" ::: "memory");
}

// ---------------- prep: cast 5 weight tensors fp32->bf16, zero flags ------------
__global__ void cast5_kernel(const float* __restrict__ s0, const float* __restrict__ s1,
                             const float* __restrict__ s2, const float* __restrict__ s3,
                             const float* __restrict__ s4,
                             u16* __restrict__ d0, u16* __restrict__ d1,
                             u16* __restrict__ d2, u16* __restrict__ d3,
                             u16* __restrict__ d4, unsigned* __restrict__ flags) {
  if (blockIdx.x == 0) {
#pragma unroll
    for (int k = 0; k < 64; ++k) flags[threadIdx.x * 64 + k] = 0;  // 64 KB of flags
  }
  int bid = blockIdx.x;
  const float* s; u16* d; size_t base;
  if (bid < 3072)       { s = s0; d = d0; base = (size_t)bid * 1024; }
  else if (bid < 6144)  { s = s1; d = d1; base = (size_t)(bid - 3072) * 1024; }
  else if (bid < 9216)  { s = s2; d = d2; base = (size_t)(bid - 6144) * 1024; }
  else if (bid < 12288) { s = s3; d = d3; base = (size_t)(bid - 9216) * 1024; }
  else                  { s = s4; d = d4; base = (size_t)(bid - 12288) * 1024; }
  size_t i = base + (size_t)threadIdx.x * 4;
  float4 v = *(const float4*)(s + i);
  unsigned lo = (unsigned)f2bf(v.x) | ((unsigned)f2bf(v.y) << 16);
  unsigned hi = (unsigned)f2bf(v.z) | ((unsigned)f2bf(v.w) << 16);
  uint2 o; o.x = lo; o.y = hi;
  *(uint2*)(d + i) = o;
}

// ---------------- embedding gather + cast to bf16 ------------------------------
__global__ void gather_cast_kernel(const int* __restrict__ tokens,
                                   const float* __restrict__ emb,
                                   u16* __restrict__ xbf) {
  int row = blockIdx.x;                 // 0..16383  (= b*T + t)
  int tok = tokens[row];
  const float4* src = (const float4*)(emb + (size_t)tok * HDIM);
  float4 v = src[threadIdx.x];
  unsigned lo = (unsigned)f2bf(v.x) | ((unsigned)f2bf(v.y) << 16);
  unsigned hi = (unsigned)f2bf(v.z) | ((unsigned)f2bf(v.w) << 16);
  uint2 o; o.x = lo; o.y = hi;
  *(uint2*)(xbf + (size_t)row * HDIM + (size_t)threadIdx.x * 4) = o;
}

// ---------------- bf16 MFMA GEMM, C[m,n] = sum_k A[m,k]*Bt[n,k] -----------------
// A_PACKED: A is the packed scan layout h[t][prod][b][16]; logical row r = b*T+t
// maps to slot t+1 (state after step t).
// OUT_MODE 0: fp32 plain [m*N+n].  OUT_MODE 2: bf16 gx-packed gx[t][wg][gate][b][ej].
template <int OUT_MODE, bool A_PACKED, bool ADD_BIAS>
__global__ __launch_bounds__(256)
void gemm_bt(const u16* __restrict__ A, const u16* __restrict__ Bt,
             void* __restrict__ Cout, const float* __restrict__ bias,
             int M, int N) {
  const int K = 1024;
  __shared__ u16 As[128 * 32];
  __shared__ u16 Bs[128 * 32];
  const int tid = threadIdx.x;
  const int wave = tid >> 6, lane = tid & 63;
  const int quad = lane >> 4, l16 = lane & 15;
  const int wm = (wave & 1) * 64, wn = (wave >> 1) * 64;
  const int m0 = blockIdx.x * 128, n0 = blockIdx.y * 128;
  const int srow = tid >> 2, scol = (tid & 3) * 8;

  size_t abase0, abase1;
  {
    int r0 = m0 + srow, r1 = m0 + 64 + srow;
    if (A_PACKED) {
      abase0 = (size_t)((r0 & 1023) + 1) * SLOT + (size_t)(r0 >> 10) * 16 +
               (size_t)(scol & 8) + (size_t)(scol >> 4) * 256;
      abase1 = (size_t)((r1 & 1023) + 1) * SLOT + (size_t)(r1 >> 10) * 16 +
               (size_t)(scol & 8) + (size_t)(scol >> 4) * 256;
    } else {
      abase0 = (size_t)r0 * K + scol;
      abase1 = (size_t)r1 * K + scol;
    }
  }
  const size_t bbase0 = (size_t)(n0 + srow) * K + scol;
  const size_t bbase1 = (size_t)(n0 + 64 + srow) * K + scol;

  f32x4 acc[4][4] = {};

  for (int kk = 0; kk < K; kk += 32) {
    __syncthreads();
    size_t ka = A_PACKED ? (size_t)kk * 16 : (size_t)kk;   // 32 cols = 2 strips = 512 elems
    gld16(&As[srow * 32 + scol],        A + abase0 + ka);
    gld16(&As[(64 + srow) * 32 + scol], A + abase1 + ka);
    gld16(&Bs[srow * 32 + scol],        Bt + bbase0 + kk);
    gld16(&Bs[(64 + srow) * 32 + scol], Bt + bbase1 + kk);
    __syncthreads();
    short8 af[4], bfr[4];
#pragma unroll
    for (int mt = 0; mt < 4; ++mt)
      af[mt] = *(const short8*)&As[(wm + mt * 16 + l16) * 32 + quad * 8];
#pragma unroll
    for (int nt = 0; nt < 4; ++nt)
      bfr[nt] = *(const short8*)&Bs[(wn + nt * 16 + l16) * 32 + quad * 8];
#pragma unroll
    for (int mt = 0; mt < 4; ++mt)
#pragma unroll
      for (int nt = 0; nt < 4; ++nt)
        acc[mt][nt] = __builtin_amdgcn_mfma_f32_16x16x32_bf16(af[mt], bfr[nt], acc[mt][nt], 0, 0, 0);
  }
#pragma unroll
  for (int mt = 0; mt < 4; ++mt) {
#pragma unroll
    for (int nt = 0; nt < 4; ++nt) {
#pragma unroll
      for (int r = 0; r < 4; ++r) {
        int m = m0 + wm + mt * 16 + quad * 4 + r;
        int n = n0 + wn + nt * 16 + l16;
        float v = acc[mt][nt][r];
        if (ADD_BIAS) v += bias[n];
        if (OUT_MODE == 2) {
          int t = m & 1023, b = m >> 10, g = n >> 10, c = n & 1023;
          size_t idx = ((((size_t)t * 64 + (c >> 4)) * 3 + g) * 16 + b) * 16 + (c & 15);
          ((u16*)Cout)[idx] = f2bf(v);
        } else {
          ((float*)Cout)[(size_t)m * N + n] = v;
        }
      }
    }
  }
}

// ---------------- fused 2-layer persistent GRU scan, 128 WGs --------------------
// R5 structure (best measured: 2885 us) + R6's proven prow swizzle (conflicts->0).
// h layout: h[t][producer wg 0..63][batch 0..15][16 cols] bf16. PER-WAVE flags:
// producer wave stores its 128 B chunk, drains with in-wave s_waitcnt vmcnt(0),
// fires its own flag. Consumer wave polls its 64 wave-flags (1/lane). One barrier
// per step (part[] double-buffered). gx packed per-(t,wg). L1 loop order is R5's:
// x-matvec -> poll1 -> af2 load -> af1 prefetch (mid-loop: laggard has slack here)
// -> h-MFMA -> part -> barrier -> reduce/gates -> store/drain/flag.
__global__ __launch_bounds__(256, 1)
void fused_scan_kernel(const u16* __restrict__ gx0,
                       u16* __restrict__ h1seq, u16* __restrict__ h2seq,
                       const u16* __restrict__ Whh0, const u16* __restrict__ Wih1,
                       const u16* __restrict__ Whh1,
                       const float* __restrict__ bih0, const float* __restrict__ bhh0,
                       const float* __restrict__ bih1, const float* __restrict__ bhh1,
                       unsigned* __restrict__ flags0, unsigned* __restrict__ flags1) {
  const int tid = threadIdx.x;
  const int wave = tid >> 6, lane = tid & 63;
  const int quad = lane >> 4, l16 = lane & 15;
  const int eb = tid >> 4, ej = tid & 15;

  __shared__ float part[2][4][6][256];         // 48 KB, double-buffered
  __shared__ float biasS[2][3][16];
  __shared__ u16 wx[4 * 3 * 8 * 4 * 16 * 8];   // 96 KB, layer-1 Wih1 slice

  // fragment source offset within a slot: prod = 16w + 2s + (quad>>1),
  // elem = prod*256 + batch(l16)*16 + (quad&1)*8 ; + s*512 per k-subtile
  const int fragoff = (16 * wave + (quad >> 1)) * 256 + l16 * 16 + (quad & 1) * 8;
  const int rdo = prow(eb) * 16 + ej;          // swizzled part[] read offset

  if (blockIdx.x < 64) {
    // ======================= LAYER 0 =======================
    const int wg = blockIdx.x, j0 = wg * 16;
    short8 wf[3][8];
#pragma unroll
    for (int g = 0; g < 3; ++g)
#pragma unroll
      for (int s = 0; s < 8; ++s)
        wf[g][s] = *(const short8*)&Whh0[(size_t)(g * 1024 + j0 + l16) * 1024 + wave * 256 + s * 32 + quad * 8];
    if (tid < 96) {
      int a = tid / 48, rem = tid % 48, g = rem >> 4, jl = rem & 15;
      biasS[a][g][jl] = (a ? bhh0 : bih0)[g * 1024 + j0 + jl];
    }
    // zero own 128B chunk of slot 0, drain, per-wave flag = 1
    if (lane < 32) st_agent_u32((unsigned*)h1seq + wg * 128 + wave * 32 + lane, 0u);
    asm volatile("s_waitcnt vmcnt(0)" ::: "memory");
    if (lane == 0) st_agent_u32(flags0 + (size_t)(wg * 4 + wave) * FSTRIDE, 1u);

    const u16* gxp = gx0 + (size_t)(wg * 3) * 256 + eb * 16 + ej;   // t = 0
    u16 gxu0 = gxp[0], gxu1 = gxp[256], gxu2 = gxp[512];
    float hprev = 0.f;

    for (int t = 0; t < T_SEQ; ++t) {
      const int pb = t & 1;
      poll64(flags0, wave, lane, (unsigned)(t + 1));
      const u16* src = h1seq + (size_t)t * SLOT + fragoff;
      short8 af[8];
#pragma unroll
      for (int s = 0; s < 8; ++s) af[s] = *(const short8*)(src + s * 512);
      f32x4 a0 = {0.f,0.f,0.f,0.f}, a1 = {0.f,0.f,0.f,0.f}, a2 = {0.f,0.f,0.f,0.f};
#pragma unroll
      for (int s = 0; s < 8; ++s) {
        a0 = __builtin_amdgcn_mfma_f32_16x16x32_bf16(af[s], wf[0][s], a0, 0, 0, 0);
        a1 = __builtin_amdgcn_mfma_f32_16x16x32_bf16(af[s], wf[1][s], a1, 0, 0, 0);
        a2 = __builtin_amdgcn_mfma_f32_16x16x32_bf16(af[s], wf[2][s], a2, 0, 0, 0);
      }
#pragma unroll
      for (int r = 0; r < 4; ++r) {
        int o = prow(quad * 4 + r) * 16 + l16;
        part[pb][wave][0][o] = a0[r]; part[pb][wave][1][o] = a1[r]; part[pb][wave][2][o] = a2[r];
      }
      __syncthreads();   // the ONE barrier per step
      float ghr = part[pb][0][0][rdo] + part[pb][1][0][rdo] + part[pb][2][0][rdo] + part[pb][3][0][rdo] + biasS[1][0][ej];
      float ghz = part[pb][0][1][rdo] + part[pb][1][1][rdo] + part[pb][2][1][rdo] + part[pb][3][1][rdo] + biasS[1][1][ej];
      float ghn = part[pb][0][2][rdo] + part[pb][1][2][rdo] + part[pb][2][2][rdo] + part[pb][3][2][rdo] + biasS[1][2][ej];
      float xr = bf2f(gxu0) + biasS[0][0][ej] + ghr;
      float xz = bf2f(gxu1) + biasS[0][1][ej] + ghz;
      float xn = bf2f(gxu2) + biasS[0][2][ej];
      float r_ = 1.f / (1.f + __expf(-xr));
      float z_ = 1.f / (1.f + __expf(-xz));
      float pre = fminf(fmaxf(xn + r_ * ghn, -15.f), 15.f);
      float e2 = __expf(2.f * pre);
      float n_ = (e2 - 1.f) / (e2 + 1.f);
      float hn = (1.f - z_) * n_ + z_ * hprev;
      hprev = hn;

      unsigned mine = (unsigned)f2bf(hn);
      unsigned other = __shfl_xor(mine, 1);
      if (!(tid & 1))
        st_agent_u32((unsigned*)h1seq + (size_t)(t + 1) * (SLOT / 2) + wg * 128 + (tid >> 1),
                     mine | (other << 16));
      asm volatile("s_waitcnt vmcnt(0)" ::: "memory");   // per-wave drain of h stores
      if (lane == 0)
        st_agent_u32(flags0 + (size_t)(wg * 4 + wave) * FSTRIDE, (unsigned)(t + 2));
      // prefetch next step's packed gx (after flag so it never delays it)
      int tn = (t + 1 < T_SEQ) ? t + 1 : t;
      const u16* gpn = gx0 + (size_t)(tn * 64 + wg) * 3 * 256 + eb * 16 + ej;
      gxu0 = gpn[0]; gxu1 = gpn[256]; gxu2 = gpn[512];
    }
  } else {
    // ======================= LAYER 1 =======================
    const int wg = blockIdx.x - 64, j0 = wg * 16;
    short8 wfH[3][8];
#pragma unroll
    for (int g = 0; g < 3; ++g)
#pragma unroll
      for (int s = 0; s < 8; ++s) {
        size_t row = (size_t)(g * 1024 + j0 + l16) * 1024 + wave * 256 + s * 32 + quad * 8;
        wfH[g][s] = *(const short8*)&Whh1[row];
        // stage Wih1 fragment to LDS (each lane writes+reads its own slot; no barrier needed)
        short8 wv = *(const short8*)&Wih1[row];
        *(short8*)&wx[((((wave * 3 + g) * 8 + s) * 4 + quad) * 16 + l16) * 8] = wv;
      }
    if (tid < 96) {
      int a = tid / 48, rem = tid % 48, g = rem >> 4, jl = rem & 15;
      biasS[a][g][jl] = (a ? bhh1 : bih1)[g * 1024 + j0 + jl];
    }
    if (lane < 32) st_agent_u32((unsigned*)h2seq + wg * 128 + wave * 32 + lane, 0u);
    asm volatile("s_waitcnt vmcnt(0)" ::: "memory");
    if (lane == 0) st_agent_u32(flags1 + (size_t)(wg * 4 + wave) * FSTRIDE, 1u);

    float hprev = 0.f;
    short8 af1[8];
    poll64(flags0, wave, lane, 2u);            // h1 gen 1 ready
    {
      const u16* s1 = h1seq + (size_t)SLOT + fragoff;
#pragma unroll
      for (int s = 0; s < 8; ++s) af1[s] = *(const short8*)(s1 + s * 512);
    }

    for (int t = 0; t < T_SEQ; ++t) {
      const int pb = t & 1;
      // x-matvec on preloaded af1 (Wih1 fragments from LDS)
      f32x4 x0 = {0.f,0.f,0.f,0.f}, x1 = {0.f,0.f,0.f,0.f}, x2 = {0.f,0.f,0.f,0.f};
#pragma unroll
      for (int s = 0; s < 8; ++s) {
        short8 w0 = *(const short8*)&wx[((((wave * 3 + 0) * 8 + s) * 4 + quad) * 16 + l16) * 8];
        short8 w1 = *(const short8*)&wx[((((wave * 3 + 1) * 8 + s) * 4 + quad) * 16 + l16) * 8];
        short8 w2 = *(const short8*)&wx[((((wave * 3 + 2) * 8 + s) * 4 + quad) * 16 + l16) * 8];
        x0 = __builtin_amdgcn_mfma_f32_16x16x32_bf16(af1[s], w0, x0, 0, 0, 0);
        x1 = __builtin_amdgcn_mfma_f32_16x16x32_bf16(af1[s], w1, x1, 0, 0, 0);
        x2 = __builtin_amdgcn_mfma_f32_16x16x32_bf16(af1[s], w2, x2, 0, 0, 0);
      }
      // h2[t] handoff (own layer, lockstep)
      poll64(flags1, wave, lane, (unsigned)(t + 1));
      short8 af2[8];
      const u16* s2 = h2seq + (size_t)t * SLOT + fragoff;
#pragma unroll
      for (int s = 0; s < 8; ++s) af2[s] = *(const short8*)(s2 + s * 512);
      // prefetch next h1 gen (slot t+2) MID-LOOP: the laggard WG has slack here
      // (h-MFMA + barrier + gates below cover the load latency) — R6 proved
      // moving this to the loop tail costs ~650 us.
      if (t + 1 < T_SEQ) {
        poll64(flags0, wave, lane, (unsigned)(t + 3));
        const u16* s1 = h1seq + (size_t)(t + 2) * SLOT + fragoff;
#pragma unroll
        for (int s = 0; s < 8; ++s) af1[s] = *(const short8*)(s1 + s * 512);
      }
      f32x4 h0 = {0.f,0.f,0.f,0.f}, h1a = {0.f,0.f,0.f,0.f}, h2a = {0.f,0.f,0.f,0.f};
#pragma unroll
      for (int s = 0; s < 8; ++s) {
        h0  = __builtin_amdgcn_mfma_f32_16x16x32_bf16(af2[s], wfH[0][s], h0, 0, 0, 0);
        h1a = __builtin_amdgcn_mfma_f32_16x16x32_bf16(af2[s], wfH[1][s], h1a, 0, 0, 0);
        h2a = __builtin_amdgcn_mfma_f32_16x16x32_bf16(af2[s], wfH[2][s], h2a, 0, 0, 0);
      }
#pragma unroll
      for (int r = 0; r < 4; ++r) {
        int o = prow(quad * 4 + r) * 16 + l16;
        part[pb][wave][0][o] = x0[r];  part[pb][wave][1][o] = x1[r];  part[pb][wave][2][o] = x2[r];
        part[pb][wave][3][o] = h0[r];  part[pb][wave][4][o] = h1a[r]; part[pb][wave][5][o] = h2a[r];
      }
      __syncthreads();
      float sxr = part[pb][0][0][rdo] + part[pb][1][0][rdo] + part[pb][2][0][rdo] + part[pb][3][0][rdo] + biasS[0][0][ej];
      float sxz = part[pb][0][1][rdo] + part[pb][1][1][rdo] + part[pb][2][1][rdo] + part[pb][3][1][rdo] + biasS[0][1][ej];
      float sxn = part[pb][0][2][rdo] + part[pb][1][2][rdo] + part[pb][2][2][rdo] + part[pb][3][2][rdo] + biasS[0][2][ej];
      float shr = part[pb][0][3][rdo] + part[pb][1][3][rdo] + part[pb][2][3][rdo] + part[pb][3][3][rdo] + biasS[1][0][ej];
      float shz = part[pb][0][4][rdo] + part[pb][1][4][rdo] + part[pb][2][4][rdo] + part[pb][3][4][rdo] + biasS[1][1][ej];
      float shn = part[pb][0][5][rdo] + part[pb][1][5][rdo] + part[pb][2][5][rdo] + part[pb][3][5][rdo] + biasS[1][2][ej];
      float r_ = 1.f / (1.f + __expf(-(sxr + shr)));
      float z_ = 1.f / (1.f + __expf(-(sxz + shz)));
      float pre = fminf(fmaxf(sxn + r_ * shn, -15.f), 15.f);
      float e2 = __expf(2.f * pre);
      float n_ = (e2 - 1.f) / (e2 + 1.f);
      float hn = (1.f - z_) * n_ + z_ * hprev;
      hprev = hn;

      unsigned mine = (unsigned)f2bf(hn);
      unsigned other = __shfl_xor(mine, 1);
      if (!(tid & 1))
        st_agent_u32((unsigned*)h2seq + (size_t)(t + 1) * (SLOT / 2) + wg * 128 + (tid >> 1),
                     mine | (other << 16));
      asm volatile("s_waitcnt vmcnt(0)" ::: "memory");   // drains h2 stores (+ af1 prefetch)
      if (lane == 0)
        st_agent_u32(flags1 + (size_t)(wg * 4 + wave) * FSTRIDE, (unsigned)(t + 2));
    }
  }
}

// ---------------- log_softmax over axis=1 (T): grid (16 b, 8 cgroups) ----------
__global__ void logsoftmax_kernel(float* __restrict__ out) {
  int b = blockIdx.x, cg = blockIdx.y;
  int ci = threadIdx.x & 15, ts = threadIdx.x >> 4;   // 16 cols x 16 t-strips
  int c = cg * 16 + ci;
  float m = -1e30f, s = 0.f;
  for (int t = ts; t < T_SEQ; t += 16) {
    float v = out[((size_t)b * T_SEQ + t) * 128 + c];
    if (v > m) { s = s * __expf(m - v) + 1.f; m = v; }
    else s += __expf(v - m);
  }
  __shared__ float mS[16][16], sS[16][16];
  mS[ts][ci] = m; sS[ts][ci] = s;
  __syncthreads();
  if (ts == 0) {
    float M = mS[0][ci], S = sS[0][ci];
#pragma unroll
    for (int k = 1; k < 16; ++k) {
      float m2 = mS[k][ci], s2 = sS[k][ci];
      float nm = fmaxf(M, m2);
      S = S * __expf(M - nm) + s2 * __expf(m2 - nm);
      M = nm;
    }
    sS[0][ci] = M + logf(S);
  }
  __syncthreads();
  float lsd = sS[0][ci];
  for (int t = ts; t < T_SEQ; t += 16) {
    size_t i = ((size_t)b * T_SEQ + t) * 128 + c;
    out[i] -= lsd;
  }
}

// --------------------------------------------------------------------------------
extern "C" void kernel_launch(void* const* d_in, const int* in_sizes, int n_in,
                              void* d_out, int out_size, void* d_ws, size_t ws_size,
                              hipStream_t stream) {
  const int*   tokens = (const int*)d_in[0];
  const float* emb  = (const float*)d_in[1];
  const float* Wih0 = (const float*)d_in[2];
  const float* Whh0 = (const float*)d_in[3];
  const float* bih0 = (const float*)d_in[4];
  const float* bhh0 = (const float*)d_in[5];
  const float* Wih1 = (const float*)d_in[6];
  const float* Whh1 = (const float*)d_in[7];
  const float* bih1 = (const float*)d_in[8];
  const float* bhh1 = (const float*)d_in[9];
  const float* Wlin = (const float*)d_in[10];
  const float* blin = (const float*)d_in[11];
  float* out = (float*)d_out;

  uint8_t* ws = (uint8_t*)d_ws;
  size_t off = 0;
  auto alloc = [&](size_t bytes) -> void* {
    void* p = ws + off;
    off += (bytes + 255) & ~(size_t)255;
    return p;
  };
  u16* h1seq = (u16*)alloc((size_t)(T_SEQ + 1) * SLOT * 2);  // also holds x_bf pre-scan
  u16* h2seq = (u16*)alloc((size_t)(T_SEQ + 1) * SLOT * 2);
  u16* gxbuf = (u16*)alloc((size_t)16384 * NG * 2);          // packed gx[t][wg][g][b][ej]
  u16* wih0b = (u16*)alloc((size_t)NG * HDIM * 2);
  u16* whh0b = (u16*)alloc((size_t)NG * HDIM * 2);
  u16* wih1b = (u16*)alloc((size_t)NG * HDIM * 2);
  u16* whh1b = (u16*)alloc((size_t)NG * HDIM * 2);
  u16* wlinb = (u16*)alloc((size_t)128 * HDIM * 2);
  unsigned* flags = (unsigned*)alloc(65536);   // flags0 = 256 wave-flags, flags1 next

  cast5_kernel<<<dim3(12416), dim3(256), 0, stream>>>(
      Wih0, Whh0, Wih1, Whh1, Wlin, wih0b, whh0b, wih1b, whh1b, wlinb, flags);
  gather_cast_kernel<<<dim3(16384), dim3(256), 0, stream>>>(tokens, emb, h1seq);
  // gx0 = x @ W_ih0^T, written consumer-packed
  gemm_bt<2, false, false><<<dim3(128, 24), dim3(256), 0, stream>>>(
      h1seq, wih0b, gxbuf, nullptr, 16384, NG);
  // fused 2-layer scan (R5 pipeline + prow swizzle)
  fused_scan_kernel<<<dim3(128), dim3(256), 0, stream>>>(
      gxbuf, h1seq, h2seq, whh0b, wih1b, whh1b, bih0, bhh0, bih1, bhh1,
      flags, flags + 256 * FSTRIDE);
  // logits = h2 @ W_lin^T + b_lin -> d_out (fp32); A read from packed h2 slots
  gemm_bt<0, true, true><<<dim3(128, 1), dim3(256), 0, stream>>>(
      h2seq, wlinb, out, blin, 16384, 128);
  // log_softmax over T, in place
  logsoftmax_kernel<<<dim3(16, 8), dim3(256), 0, stream>>>(out);
}

// Round 9
// 3134.417 us; speedup vs baseline: 1.3290x; 1.0489x over previous
//
#include <hip/hip_runtime.h>
#include <stdint.h>

typedef unsigned short u16;
typedef unsigned int u32;
typedef unsigned long long u64;
typedef __attribute__((ext_vector_type(8))) short short8;
typedef __attribute__((ext_vector_type(4))) float f32x4;

#define T_SEQ 1024
#define HDIM  1024
#define NG    3072
#define SLOT  16384          // u16 elements per time-slot: 64 strips * 16 batch * 16 cols
#define FSTRIDE 32           // u32 stride between WG flag lines (128 B, own line)

__device__ __forceinline__ u16 f2bf(float f) {
  unsigned u = __float_as_uint(f);
  u += 0x7FFF + ((u >> 16) & 1);
  return (u16)(u >> 16);
}
__device__ __forceinline__ float bf2f(u16 h) {
  return __uint_as_float(((unsigned)h) << 16);
}

// bank-conflict-free part[] row permutation (proven in R6: conflicts 1.9e7 -> 0)
__device__ __forceinline__ int prow(int b) { return b ^ ((b >> 2) & 1); }

// async global->LDS, 16B per lane (GEMM staging only). LDS dest = uniform base + lane*16.
__device__ __forceinline__ void gld16(void* lds, const void* g) {
  __builtin_amdgcn_global_load_lds(
      (const __attribute__((address_space(1))) unsigned*)g,
      (__attribute__((address_space(3))) unsigned*)lds, 16, 0, 0);
}

__device__ __forceinline__ void st_agent_u32(unsigned* p, unsigned v) {
  __hip_atomic_store(p, v, __ATOMIC_RELAXED, __HIP_MEMORY_SCOPE_AGENT);
}
__device__ __forceinline__ void st_agent_u64(u64* p, u64 v) {
  __hip_atomic_store(p, v, __ATOMIC_RELAXED, __HIP_MEMORY_SCOPE_AGENT);
}
__device__ __forceinline__ unsigned ld_agent_u32(const unsigned* p) {
  return __hip_atomic_load(p, __ATOMIC_RELAXED, __HIP_MEMORY_SCOPE_AGENT);
}

// wave flag for (wg, wv) lives at flags[wg*FSTRIDE + wv]: one 128B line per WG.
// Consumer wave w needs producers 16w..16w+15 x 4 wave-flags = 64 flags in 16
// lines (4 lanes/line). 4x less poll traffic than line-per-flag.
__device__ __forceinline__ void poll64(const unsigned* flags, int wave, int lane, unsigned need) {
  const unsigned* f = flags + (size_t)(16 * wave + (lane >> 2)) * FSTRIDE + (lane & 3);
  while (ld_agent_u32(f) < need) {}
  asm volatile("" ::: "memory");
}

// ---------------- prep: cast 5 weight tensors fp32->bf16, zero flags ------------
__global__ void cast5_kernel(const float* __restrict__ s0, const float* __restrict__ s1,
                             const float* __restrict__ s2, const float* __restrict__ s3,
                             const float* __restrict__ s4,
                             u16* __restrict__ d0, u16* __restrict__ d1,
                             u16* __restrict__ d2, u16* __restrict__ d3,
                             u16* __restrict__ d4, unsigned* __restrict__ flags) {
  if (blockIdx.x == 0) {
#pragma unroll
    for (int k = 0; k < 64; ++k) flags[threadIdx.x * 64 + k] = 0;  // 64 KB of flags
  }
  int bid = blockIdx.x;
  const float* s; u16* d; size_t base;
  if (bid < 3072)       { s = s0; d = d0; base = (size_t)bid * 1024; }
  else if (bid < 6144)  { s = s1; d = d1; base = (size_t)(bid - 3072) * 1024; }
  else if (bid < 9216)  { s = s2; d = d2; base = (size_t)(bid - 6144) * 1024; }
  else if (bid < 12288) { s = s3; d = d3; base = (size_t)(bid - 9216) * 1024; }
  else                  { s = s4; d = d4; base = (size_t)(bid - 12288) * 1024; }
  size_t i = base + (size_t)threadIdx.x * 4;
  float4 v = *(const float4*)(s + i);
  unsigned lo = (unsigned)f2bf(v.x) | ((unsigned)f2bf(v.y) << 16);
  unsigned hi = (unsigned)f2bf(v.z) | ((unsigned)f2bf(v.w) << 16);
  uint2 o; o.x = lo; o.y = hi;
  *(uint2*)(d + i) = o;
}

// ---------------- embedding gather + cast to bf16 ------------------------------
__global__ void gather_cast_kernel(const int* __restrict__ tokens,
                                   const float* __restrict__ emb,
                                   u16* __restrict__ xbf) {
  int row = blockIdx.x;                 // 0..16383  (= b*T + t)
  int tok = tokens[row];
  const float4* src = (const float4*)(emb + (size_t)tok * HDIM);
  float4 v = src[threadIdx.x];
  unsigned lo = (unsigned)f2bf(v.x) | ((unsigned)f2bf(v.y) << 16);
  unsigned hi = (unsigned)f2bf(v.z) | ((unsigned)f2bf(v.w) << 16);
  uint2 o; o.x = lo; o.y = hi;
  *(uint2*)(xbf + (size_t)row * HDIM + (size_t)threadIdx.x * 4) = o;
}

// ---------------- bf16 MFMA GEMM, C[m,n] = sum_k A[m,k]*Bt[n,k] -----------------
// A_PACKED: A is the packed scan layout h[t][prod][b][16]; logical row r = b*T+t
// maps to slot t+1 (state after step t).
// OUT_MODE 0: fp32 plain [m*N+n].  OUT_MODE 2: bf16 gx-packed gx[t][wg][gate][b][ej].
template <int OUT_MODE, bool A_PACKED, bool ADD_BIAS>
__global__ __launch_bounds__(256)
void gemm_bt(const u16* __restrict__ A, const u16* __restrict__ Bt,
             void* __restrict__ Cout, const float* __restrict__ bias,
             int M, int N) {
  const int K = 1024;
  __shared__ u16 As[128 * 32];
  __shared__ u16 Bs[128 * 32];
  const int tid = threadIdx.x;
  const int wave = tid >> 6, lane = tid & 63;
  const int quad = lane >> 4, l16 = lane & 15;
  const int wm = (wave & 1) * 64, wn = (wave >> 1) * 64;
  const int m0 = blockIdx.x * 128, n0 = blockIdx.y * 128;
  const int srow = tid >> 2, scol = (tid & 3) * 8;

  size_t abase0, abase1;
  {
    int r0 = m0 + srow, r1 = m0 + 64 + srow;
    if (A_PACKED) {
      abase0 = (size_t)((r0 & 1023) + 1) * SLOT + (size_t)(r0 >> 10) * 16 +
               (size_t)(scol & 8) + (size_t)(scol >> 4) * 256;
      abase1 = (size_t)((r1 & 1023) + 1) * SLOT + (size_t)(r1 >> 10) * 16 +
               (size_t)(scol & 8) + (size_t)(scol >> 4) * 256;
    } else {
      abase0 = (size_t)r0 * K + scol;
      abase1 = (size_t)r1 * K + scol;
    }
  }
  const size_t bbase0 = (size_t)(n0 + srow) * K + scol;
  const size_t bbase1 = (size_t)(n0 + 64 + srow) * K + scol;

  f32x4 acc[4][4] = {};

  for (int kk = 0; kk < K; kk += 32) {
    __syncthreads();
    size_t ka = A_PACKED ? (size_t)kk * 16 : (size_t)kk;   // 32 cols = 2 strips = 512 elems
    gld16(&As[srow * 32 + scol],        A + abase0 + ka);
    gld16(&As[(64 + srow) * 32 + scol], A + abase1 + ka);
    gld16(&Bs[srow * 32 + scol],        Bt + bbase0 + kk);
    gld16(&Bs[(64 + srow) * 32 + scol], Bt + bbase1 + kk);
    __syncthreads();
    short8 af[4], bfr[4];
#pragma unroll
    for (int mt = 0; mt < 4; ++mt)
      af[mt] = *(const short8*)&As[(wm + mt * 16 + l16) * 32 + quad * 8];
#pragma unroll
    for (int nt = 0; nt < 4; ++nt)
      bfr[nt] = *(const short8*)&Bs[(wn + nt * 16 + l16) * 32 + quad * 8];
#pragma unroll
    for (int mt = 0; mt < 4; ++mt)
#pragma unroll
      for (int nt = 0; nt < 4; ++nt)
        acc[mt][nt] = __builtin_amdgcn_mfma_f32_16x16x32_bf16(af[mt], bfr[nt], acc[mt][nt], 0, 0, 0);
  }
#pragma unroll
  for (int mt = 0; mt < 4; ++mt) {
#pragma unroll
    for (int nt = 0; nt < 4; ++nt) {
#pragma unroll
      for (int r = 0; r < 4; ++r) {
        int m = m0 + wm + mt * 16 + quad * 4 + r;
        int n = n0 + wn + nt * 16 + l16;
        float v = acc[mt][nt][r];
        if (ADD_BIAS) v += bias[n];
        if (OUT_MODE == 2) {
          int t = m & 1023, b = m >> 10, g = n >> 10, c = n & 1023;
          size_t idx = ((((size_t)t * 64 + (c >> 4)) * 3 + g) * 16 + b) * 16 + (c & 15);
          ((u16*)Cout)[idx] = f2bf(v);
        } else {
          ((float*)Cout)[(size_t)m * N + n] = v;
        }
      }
    }
  }
}

// ---------------- fused 2-layer persistent GRU scan, 128 WGs --------------------
// R8 structure (proven ~2900 us) + packed flag lines (4x less poll traffic) +
// u64 strip stores (half the store messages per drain).
__global__ __launch_bounds__(256, 1)
void fused_scan_kernel(const u16* __restrict__ gx0,
                       u16* __restrict__ h1seq, u16* __restrict__ h2seq,
                       const u16* __restrict__ Whh0, const u16* __restrict__ Wih1,
                       const u16* __restrict__ Whh1,
                       const float* __restrict__ bih0, const float* __restrict__ bhh0,
                       const float* __restrict__ bih1, const float* __restrict__ bhh1,
                       unsigned* __restrict__ flags0, unsigned* __restrict__ flags1) {
  const int tid = threadIdx.x;
  const int wave = tid >> 6, lane = tid & 63;
  const int quad = lane >> 4, l16 = lane & 15;
  const int eb = tid >> 4, ej = tid & 15;

  __shared__ float part[2][4][6][256];         // 48 KB, double-buffered
  __shared__ float biasS[2][3][16];
  __shared__ u16 wx[4 * 3 * 8 * 4 * 16 * 8];   // 96 KB, layer-1 Wih1 slice

  // fragment source offset within a slot: prod = 16w + 2s + (quad>>1),
  // elem = prod*256 + batch(l16)*16 + (quad&1)*8 ; + s*512 per k-subtile
  const int fragoff = (16 * wave + (quad >> 1)) * 256 + l16 * 16 + (quad & 1) * 8;
  const int rdo = prow(eb) * 16 + ej;          // swizzled part[] read offset

  if (blockIdx.x < 64) {
    // ======================= LAYER 0 =======================
    const int wg = blockIdx.x, j0 = wg * 16;
    short8 wf[3][8];
#pragma unroll
    for (int g = 0; g < 3; ++g)
#pragma unroll
      for (int s = 0; s < 8; ++s)
        wf[g][s] = *(const short8*)&Whh0[(size_t)(g * 1024 + j0 + l16) * 1024 + wave * 256 + s * 32 + quad * 8];
    if (tid < 96) {
      int a = tid / 48, rem = tid % 48, g = rem >> 4, jl = rem & 15;
      biasS[a][g][jl] = (a ? bhh0 : bih0)[g * 1024 + j0 + jl];
    }
    // zero own chunk of slot 0 (u64 stores), drain, per-wave flag = 1
    if (lane < 16) st_agent_u64((u64*)h1seq + wg * 64 + wave * 16 + lane, 0ull);
    asm volatile("s_waitcnt vmcnt(0)" ::: "memory");
    if (lane == 0) st_agent_u32(flags0 + (size_t)wg * FSTRIDE + wave, 1u);

    const u16* gxp = gx0 + (size_t)(wg * 3) * 256 + eb * 16 + ej;   // t = 0
    u16 gxu0 = gxp[0], gxu1 = gxp[256], gxu2 = gxp[512];
    float hprev = 0.f;

    for (int t = 0; t < T_SEQ; ++t) {
      const int pb = t & 1;
      poll64(flags0, wave, lane, (unsigned)(t + 1));
      const u16* src = h1seq + (size_t)t * SLOT + fragoff;
      short8 af[8];
#pragma unroll
      for (int s = 0; s < 8; ++s) af[s] = *(const short8*)(src + s * 512);
      f32x4 a0 = {0.f,0.f,0.f,0.f}, a1 = {0.f,0.f,0.f,0.f}, a2 = {0.f,0.f,0.f,0.f};
#pragma unroll
      for (int s = 0; s < 8; ++s) {
        a0 = __builtin_amdgcn_mfma_f32_16x16x32_bf16(af[s], wf[0][s], a0, 0, 0, 0);
        a1 = __builtin_amdgcn_mfma_f32_16x16x32_bf16(af[s], wf[1][s], a1, 0, 0, 0);
        a2 = __builtin_amdgcn_mfma_f32_16x16x32_bf16(af[s], wf[2][s], a2, 0, 0, 0);
      }
#pragma unroll
      for (int r = 0; r < 4; ++r) {
        int o = prow(quad * 4 + r) * 16 + l16;
        part[pb][wave][0][o] = a0[r]; part[pb][wave][1][o] = a1[r]; part[pb][wave][2][o] = a2[r];
      }
      __syncthreads();   // the ONE barrier per step
      float ghr = part[pb][0][0][rdo] + part[pb][1][0][rdo] + part[pb][2][0][rdo] + part[pb][3][0][rdo] + biasS[1][0][ej];
      float ghz = part[pb][0][1][rdo] + part[pb][1][1][rdo] + part[pb][2][1][rdo] + part[pb][3][1][rdo] + biasS[1][1][ej];
      float ghn = part[pb][0][2][rdo] + part[pb][1][2][rdo] + part[pb][2][2][rdo] + part[pb][3][2][rdo] + biasS[1][2][ej];
      float xr = bf2f(gxu0) + biasS[0][0][ej] + ghr;
      float xz = bf2f(gxu1) + biasS[0][1][ej] + ghz;
      float xn = bf2f(gxu2) + biasS[0][2][ej];
      float r_ = 1.f / (1.f + __expf(-xr));
      float z_ = 1.f / (1.f + __expf(-xz));
      float pre = fminf(fmaxf(xn + r_ * ghn, -15.f), 15.f);
      float e2 = __expf(2.f * pre);
      float n_ = (e2 - 1.f) / (e2 + 1.f);
      float hn = (1.f - z_) * n_ + z_ * hprev;
      hprev = hn;

      unsigned mine = (unsigned)f2bf(hn);
      unsigned other = __shfl_xor(mine, 1);
      unsigned pk = mine | (other << 16);          // valid on even tid
      unsigned pk2 = __shfl_xor(pk, 2);            // even tid: pk of tid+2
      if (!(tid & 3))
        st_agent_u64((u64*)h1seq + (size_t)(t + 1) * (SLOT / 4) + wg * 64 + (tid >> 2),
                     (u64)pk | ((u64)pk2 << 32));
      asm volatile("s_waitcnt vmcnt(0)" ::: "memory");   // per-wave drain of h stores
      if (lane == 0)
        st_agent_u32(flags0 + (size_t)wg * FSTRIDE + wave, (unsigned)(t + 2));
      // prefetch next step's packed gx (after flag so it never delays it)
      int tn = (t + 1 < T_SEQ) ? t + 1 : t;
      const u16* gpn = gx0 + (size_t)(tn * 64 + wg) * 3 * 256 + eb * 16 + ej;
      gxu0 = gpn[0]; gxu1 = gpn[256]; gxu2 = gpn[512];
    }
  } else {
    // ======================= LAYER 1 =======================
    const int wg = blockIdx.x - 64, j0 = wg * 16;
    short8 wfH[3][8];
#pragma unroll
    for (int g = 0; g < 3; ++g)
#pragma unroll
      for (int s = 0; s < 8; ++s) {
        size_t row = (size_t)(g * 1024 + j0 + l16) * 1024 + wave * 256 + s * 32 + quad * 8;
        wfH[g][s] = *(const short8*)&Whh1[row];
        // stage Wih1 fragment to LDS (each lane writes+reads its own slot; no barrier needed)
        short8 wv = *(const short8*)&Wih1[row];
        *(short8*)&wx[((((wave * 3 + g) * 8 + s) * 4 + quad) * 16 + l16) * 8] = wv;
      }
    if (tid < 96) {
      int a = tid / 48, rem = tid % 48, g = rem >> 4, jl = rem & 15;
      biasS[a][g][jl] = (a ? bhh1 : bih1)[g * 1024 + j0 + jl];
    }
    if (lane < 16) st_agent_u64((u64*)h2seq + wg * 64 + wave * 16 + lane, 0ull);
    asm volatile("s_waitcnt vmcnt(0)" ::: "memory");
    if (lane == 0) st_agent_u32(flags1 + (size_t)wg * FSTRIDE + wave, 1u);

    float hprev = 0.f;
    short8 af1[8];
    poll64(flags0, wave, lane, 2u);            // h1 gen 1 ready
    {
      const u16* s1 = h1seq + (size_t)SLOT + fragoff;
#pragma unroll
      for (int s = 0; s < 8; ++s) af1[s] = *(const short8*)(s1 + s * 512);
    }

    for (int t = 0; t < T_SEQ; ++t) {
      const int pb = t & 1;
      // x-matvec on preloaded af1 (Wih1 fragments from LDS)
      f32x4 x0 = {0.f,0.f,0.f,0.f}, x1 = {0.f,0.f,0.f,0.f}, x2 = {0.f,0.f,0.f,0.f};
#pragma unroll
      for (int s = 0; s < 8; ++s) {
        short8 w0 = *(const short8*)&wx[((((wave * 3 + 0) * 8 + s) * 4 + quad) * 16 + l16) * 8];
        short8 w1 = *(const short8*)&wx[((((wave * 3 + 1) * 8 + s) * 4 + quad) * 16 + l16) * 8];
        short8 w2 = *(const short8*)&wx[((((wave * 3 + 2) * 8 + s) * 4 + quad) * 16 + l16) * 8];
        x0 = __builtin_amdgcn_mfma_f32_16x16x32_bf16(af1[s], w0, x0, 0, 0, 0);
        x1 = __builtin_amdgcn_mfma_f32_16x16x32_bf16(af1[s], w1, x1, 0, 0, 0);
        x2 = __builtin_amdgcn_mfma_f32_16x16x32_bf16(af1[s], w2, x2, 0, 0, 0);
      }
      // h2[t] handoff (own layer, lockstep)
      poll64(flags1, wave, lane, (unsigned)(t + 1));
      short8 af2[8];
      const u16* s2 = h2seq + (size_t)t * SLOT + fragoff;
#pragma unroll
      for (int s = 0; s < 8; ++s) af2[s] = *(const short8*)(s2 + s * 512);
      // prefetch next h1 gen (slot t+2) MID-LOOP: the laggard WG has slack here
      // (h-MFMA + barrier + gates below cover the load latency) — R6 proved
      // moving this to the loop tail costs ~650 us.
      if (t + 1 < T_SEQ) {
        poll64(flags0, wave, lane, (unsigned)(t + 3));
        const u16* s1 = h1seq + (size_t)(t + 2) * SLOT + fragoff;
#pragma unroll
        for (int s = 0; s < 8; ++s) af1[s] = *(const short8*)(s1 + s * 512);
      }
      f32x4 h0 = {0.f,0.f,0.f,0.f}, h1a = {0.f,0.f,0.f,0.f}, h2a = {0.f,0.f,0.f,0.f};
#pragma unroll
      for (int s = 0; s < 8; ++s) {
        h0  = __builtin_amdgcn_mfma_f32_16x16x32_bf16(af2[s], wfH[0][s], h0, 0, 0, 0);
        h1a = __builtin_amdgcn_mfma_f32_16x16x32_bf16(af2[s], wfH[1][s], h1a, 0, 0, 0);
        h2a = __builtin_amdgcn_mfma_f32_16x16x32_bf16(af2[s], wfH[2][s], h2a, 0, 0, 0);
      }
#pragma unroll
      for (int r = 0; r < 4; ++r) {
        int o = prow(quad * 4 + r) * 16 + l16;
        part[pb][wave][0][o] = x0[r];  part[pb][wave][1][o] = x1[r];  part[pb][wave][2][o] = x2[r];
        part[pb][wave][3][o] = h0[r];  part[pb][wave][4][o] = h1a[r]; part[pb][wave][5][o] = h2a[r];
      }
      __syncthreads();
      float sxr = part[pb][0][0][rdo] + part[pb][1][0][rdo] + part[pb][2][0][rdo] + part[pb][3][0][rdo] + biasS[0][0][ej];
      float sxz = part[pb][0][1][rdo] + part[pb][1][1][rdo] + part[pb][2][1][rdo] + part[pb][3][1][rdo] + biasS[0][1][ej];
      float sxn = part[pb][0][2][rdo] + part[pb][1][2][rdo] + part[pb][2][2][rdo] + part[pb][3][2][rdo] + biasS[0][2][ej];
      float shr = part[pb][0][3][rdo] + part[pb][1][3][rdo] + part[pb][2][3][rdo] + part[pb][3][3][rdo] + biasS[1][0][ej];
      float shz = part[pb][0][4][rdo] + part[pb][1][4][rdo] + part[pb][2][4][rdo] + part[pb][3][4][rdo] + biasS[1][1][ej];
      float shn = part[pb][0][5][rdo] + part[pb][1][5][rdo] + part[pb][2][5][rdo] + part[pb][3][5][rdo] + biasS[1][2][ej];
      float r_ = 1.f / (1.f + __expf(-(sxr + shr)));
      float z_ = 1.f / (1.f + __expf(-(sxz + shz)));
      float pre = fminf(fmaxf(sxn + r_ * shn, -15.f), 15.f);
      float e2 = __expf(2.f * pre);
      float n_ = (e2 - 1.f) / (e2 + 1.f);
      float hn = (1.f - z_) * n_ + z_ * hprev;
      hprev = hn;

      unsigned mine = (unsigned)f2bf(hn);
      unsigned other = __shfl_xor(mine, 1);
      unsigned pk = mine | (other << 16);
      unsigned pk2 = __shfl_xor(pk, 2);
      if (!(tid & 3))
        st_agent_u64((u64*)h2seq + (size_t)(t + 1) * (SLOT / 4) + wg * 64 + (tid >> 2),
                     (u64)pk | ((u64)pk2 << 32));
      asm volatile("s_waitcnt vmcnt(0)" ::: "memory");   // drains h2 stores (+ af1 prefetch)
      if (lane == 0)
        st_agent_u32(flags1 + (size_t)wg * FSTRIDE + wave, (unsigned)(t + 2));
    }
  }
}

// ---------------- log_softmax over axis=1 (T): grid (16 b, 8 cgroups) ----------
__global__ void logsoftmax_kernel(float* __restrict__ out) {
  int b = blockIdx.x, cg = blockIdx.y;
  int ci = threadIdx.x & 15, ts = threadIdx.x >> 4;   // 16 cols x 16 t-strips
  int c = cg * 16 + ci;
  float m = -1e30f, s = 0.f;
  for (int t = ts; t < T_SEQ; t += 16) {
    float v = out[((size_t)b * T_SEQ + t) * 128 + c];
    if (v > m) { s = s * __expf(m - v) + 1.f; m = v; }
    else s += __expf(v - m);
  }
  __shared__ float mS[16][16], sS[16][16];
  mS[ts][ci] = m; sS[ts][ci] = s;
  __syncthreads();
  if (ts == 0) {
    float M = mS[0][ci], S = sS[0][ci];
#pragma unroll
    for (int k = 1; k < 16; ++k) {
      float m2 = mS[k][ci], s2 = sS[k][ci];
      float nm = fmaxf(M, m2);
      S = S * __expf(M - nm) + s2 * __expf(m2 - nm);
      M = nm;
    }
    sS[0][ci] = M + logf(S);
  }
  __syncthreads();
  float lsd = sS[0][ci];
  for (int t = ts; t < T_SEQ; t += 16) {
    size_t i = ((size_t)b * T_SEQ + t) * 128 + c;
    out[i] -= lsd;
  }
}

// --------------------------------------------------------------------------------
extern "C" void kernel_launch(void* const* d_in, const int* in_sizes, int n_in,
                              void* d_out, int out_size, void* d_ws, size_t ws_size,
                              hipStream_t stream) {
  const int*   tokens = (const int*)d_in[0];
  const float* emb  = (const float*)d_in[1];
  const float* Wih0 = (const float*)d_in[2];
  const float* Whh0 = (const float*)d_in[3];
  const float* bih0 = (const float*)d_in[4];
  const float* bhh0 = (const float*)d_in[5];
  const float* Wih1 = (const float*)d_in[6];
  const float* Whh1 = (const float*)d_in[7];
  const float* bih1 = (const float*)d_in[8];
  const float* bhh1 = (const float*)d_in[9];
  const float* Wlin = (const float*)d_in[10];
  const float* blin = (const float*)d_in[11];
  float* out = (float*)d_out;

  uint8_t* ws = (uint8_t*)d_ws;
  size_t off = 0;
  auto alloc = [&](size_t bytes) -> void* {
    void* p = ws + off;
    off += (bytes + 255) & ~(size_t)255;
    return p;
  };
  u16* h1seq = (u16*)alloc((size_t)(T_SEQ + 1) * SLOT * 2);  // also holds x_bf pre-scan
  u16* h2seq = (u16*)alloc((size_t)(T_SEQ + 1) * SLOT * 2);
  u16* gxbuf = (u16*)alloc((size_t)16384 * NG * 2);          // packed gx[t][wg][g][b][ej]
  u16* wih0b = (u16*)alloc((size_t)NG * HDIM * 2);
  u16* whh0b = (u16*)alloc((size_t)NG * HDIM * 2);
  u16* wih1b = (u16*)alloc((size_t)NG * HDIM * 2);
  u16* whh1b = (u16*)alloc((size_t)NG * HDIM * 2);
  u16* wlinb = (u16*)alloc((size_t)128 * HDIM * 2);
  unsigned* flags = (unsigned*)alloc(65536);   // flags0 = 64 WG lines, flags1 next

  cast5_kernel<<<dim3(12416), dim3(256), 0, stream>>>(
      Wih0, Whh0, Wih1, Whh1, Wlin, wih0b, whh0b, wih1b, whh1b, wlinb, flags);
  gather_cast_kernel<<<dim3(16384), dim3(256), 0, stream>>>(tokens, emb, h1seq);
  // gx0 = x @ W_ih0^T, written consumer-packed
  gemm_bt<2, false, false><<<dim3(128, 24), dim3(256), 0, stream>>>(
      h1seq, wih0b, gxbuf, nullptr, 16384, NG);
  // fused 2-layer scan (R8 pipeline + packed flag lines + u64 strip stores)
  fused_scan_kernel<<<dim3(128), dim3(256), 0, stream>>>(
      gxbuf, h1seq, h2seq, whh0b, wih1b, whh1b, bih0, bhh0, bih1, bhh1,
      flags, flags + 64 * FSTRIDE);
  // logits = h2 @ W_lin^T + b_lin -> d_out (fp32); A read from packed h2 slots
  gemm_bt<0, true, true><<<dim3(128, 1), dim3(256), 0, stream>>>(
      h2seq, wlinb, out, blin, 16384, 128);
  // log_softmax over T, in place
  logsoftmax_kernel<<<dim3(16, 8), dim3(256), 0, stream>>>(out);
}